// Round 5
// baseline (216.184 us; speedup 1.0000x reference)
//
#include <hip/hip_runtime.h>

// LSTM: T=512, B=4096, IN=1, H=12.
// R15 = R14's structure with the cross-half marriage moved back to the
// HARNESS-PROVEN exchange primitive. Post-mortem R14 (FAILED absmax
// 8.2e-2): the only never-validated component was the hand-rolled
// v_permlane32_swap_b32 inline asm; everything else was structurally
// identical to passing rounds. Lesson: cross-lane exchange must use a
// primitive proven in THIS harness. R13 proved ds_swizzle_b32 xor16.
//
// Structure: 2 cells/wave -> 2048 waves = 2 waves/SIMD (grid 2048x64).
//  - cell = lane>>5, half = (lane>>4)&1, j = lane&15 (12..15 = clones).
//    Rows: r0=c0h0, r1=c0h1, r2=c1h0, r3=c1h1. Partner = lane^16 (same
//    cell, other gate-half) -> reachable by ds_swizzle (32-lane groups).
//  - half0 computes pk-pair (i,f), half1 (g,o): ONE pk-pair chain per
//    lane = 16 pkfma + init (vs R11's 34) -> per-wave issue ~halved.
//  - h[j] in registers, replicated per row; gather = R10-proven 15x DPP
//    row_ror + per-source-slot weight tables (probed direction, clone
//    sources zero-gated). No LDS on the h-recurrence chain.
//  - marriage via 3x ds_swizzle xor16 (R13-proven): tgS->half0,
//    so->half0, then hn refresh ->half1. Mirror values garbage-but-
//    finite (R13-proven analysis: r's in (0,1], c2 bounded, exp2->inf
//    absorbed by rcp; refresh overwrites before any read).
//  - fc: ring ror-reduce, DELAYED one step (R11-proven), halves split
//    into the two exp2->rcp stall windows; fake t=0 store aliases
//    out[0] then overwritten; epilogue flushes t=511.
//  - X staged per chunk (float2) to LDS [cell][time], XPAD=68; xq
//    b128 once per 4 steps, one-group-ahead prefetch.
// Budget: issue ~170-180 cyc/step/wave, chain ~210-250; wall ~
// max(chain, 2*issue) ~ 340-370 cyc vs R12's 574. Predict 85-105us.

#define TT    512
#define NB    4096
#define HH    12
#define RPW   2      // cells per wave
#define CHUNK 64     // X staging chunk; TT % CHUNK == 0
#define XPAD  68     // padded x row stride (floats)

typedef float v2f __attribute__((ext_vector_type(2)));

static __device__ __forceinline__ v2f pkfma(v2f a, v2f b, v2f c) {
#if __has_builtin(__builtin_elementwise_fma)
    return __builtin_elementwise_fma(a, b, c);
#else
    v2f r; r.x = fmaf(a.x, b.x, c.x); r.y = fmaf(a.y, b.y, c.y); return r;
#endif
}
static __device__ __forceinline__ v2f splat2(float s) { v2f r; r.x = s; r.y = s; return r; }

#define SNEG   (-1.44269504088896340736f)   // sigmoid pre-scale: -log2(e)
#define SPOS   ( 2.88539008177792681472f)   // tanh pre-scale: +2*log2(e)
#define M2SPOS (-5.77078016355585362944f)   // -2*SPOS

#define ROR(r) (0x120 + (r))                // DPP ctrl: row_ror:r
#define SWZ_XOR16 0x401F                    // BitMode: and=0x1F, xor=16

static __device__ __forceinline__ float swz16(float v) {
    return __int_as_float(__builtin_amdgcn_ds_swizzle(__float_as_int(v), SWZ_XOR16));
}

__global__ __launch_bounds__(64, 2)
void lstm_fused(const float* __restrict__ X,
                const float* __restrict__ W_ih,
                const float* __restrict__ W_hh,
                const float* __restrict__ b_ih,
                const float* __restrict__ b_hh,
                const float* __restrict__ fc_w,
                const float* __restrict__ fc_b,
                float* __restrict__ out)
{
    __shared__ __align__(16) float xchunk[RPW][XPAD]; // [cell][time]

    const int lane = threadIdx.x;          // 0..63
    const int cell = lane >> 5;            // cell within wave
    const int half = (lane >> 4) & 1;      // 0: (i,f)  1: (g,o)
    const int j    = lane & 15;            // 0..11 real, 12..15 clones
    const int cellbase = blockIdx.x * RPW;
    const int gcell = cellbase + cell;

    // ---- probe DPP ror direction: sid[r] = within-row source lane of ror r
    int sid[16];
    sid[0] = j;
#define PROBE(r) sid[r] = __builtin_amdgcn_update_dpp(0, j, ROR(r), 0xF, 0xF, true);
    PROBE(1)  PROBE(2)  PROBE(3)  PROBE(4)  PROBE(5)
    PROBE(6)  PROBE(7)  PROBE(8)  PROBE(9)  PROBE(10)
    PROBE(11) PROBE(12) PROBE(13) PROBE(14) PROBE(15)
#undef PROBE

    const int jc = (j < HH) ? j : (HH - 1);   // clamp clone lanes (finite)

    // ---- per-source-slot gate-PAIR weight tables (r=0 = local source).
    // half0: pair (i,f) both SNEG; half1: pair (g SPOS, o SNEG).
    const int   gA = (half ? 2 : 0) * HH + jc;
    const int   gB = (half ? 3 : 1) * HH + jc;
    const float sA = half ? SPOS : SNEG;
    const float* WA = W_hh + gA * HH;
    const float* WB = W_hh + gB * HH;
    v2f wU[16];
    #pragma unroll
    for (int r = 0; r < 16; ++r) {
        const int  s  = sid[r];
        const int  sc = (s < HH) ? s : (HH - 1);
        const float g = ((j >= HH) || (s < HH)) ? 1.0f : 0.0f;
        wU[r].x = g * sA   * WA[sc];
        wU[r].y = g * SNEG * WB[sc];
    }
    v2f wxv, bv;
    wxv.x = sA   * W_ih[gA];               // IN == 1, W_ih flat [48]
    wxv.y = SNEG * W_ih[gB];
    bv.x  = sA   * (b_ih[gA] + b_hh[gA]);
    bv.y  = SNEG * (b_ih[gB] + b_hh[gB]);

    const float fcb  = fc_b[0];
    const float fcwj = (j < HH) ? fc_w[j] : 0.0f;   // clones contribute 0

    float c2 = 0.0f;     // pre-scaled cell state SPOS*c (valid: half0 lanes)
    float hn = 0.0f;     // h[cell][j], replicated in both halves
    int hbits = 0;

    // delayed-output state (R11 trick)
    float pPend = 0.0f;
    unsigned offPrev = 0;
    float* const outp = out + gcell;

    // prefetch chunk 0 of X: X[t=lane][cellbase + 0..1]
    float2 gq = *(const float2*)(X + (size_t)lane * NB + cellbase);

    for (int tc = 0; tc < TT; tc += CHUNK) {
        xchunk[0][lane] = gq.x;            // cell0 row, time slot = lane
        xchunk[1][lane] = gq.y;            // cell1 row
        if (tc + CHUNK < TT)
            gq = *(const float2*)(X + (size_t)(tc + CHUNK + lane) * NB + cellbase);
        __builtin_amdgcn_wave_barrier();   // order staging vs xq reads

        float4 xq_next = *(const float4*)&xchunk[cell][0];

        for (int t4 = 0; t4 < CHUNK; t4 += 4) {
            const float4 xq = xq_next;                       // group t4
            const int nx = (t4 + 4 < CHUNK) ? (t4 + 4) : t4; // clamp tail
            xq_next = *(const float4*)&xchunk[cell][nx];
            const float xs[4] = {xq.x, xq.y, xq.z, xq.w};

            #pragma unroll
            for (int u = 0; u < 4; ++u) {
                // chain head: bias + x-proj, then local + 15 ror sources
                v2f aA = pkfma(splat2(xs[u]), wxv, bv);
                v2f aB; aB.x = 0.0f; aB.y = 0.0f;
                aA = pkfma(wU[0], splat2(hn), aA);   // local (r=0)
#define XR(r) { \
                const int hr_##r = __builtin_amdgcn_update_dpp(0, hbits, ROR(r), 0xF, 0xF, true); \
                const v2f hk = splat2(__int_as_float(hr_##r)); \
                if ((r) < 8) { aA = pkfma(wU[r], hk, aA); } \
                else         { aB = pkfma(wU[r], hk, aB); } }
                XR(1)  XR(2)  XR(3)  XR(4)  XR(5)
                XR(6)  XR(7)  XR(8)  XR(9)  XR(10)
                XR(11) XR(12) XR(13) XR(14) XR(15)
#undef XR
                const v2f a = aA + aB;               // v_pk_add_f32

                const float E0 = __builtin_amdgcn_exp2f(a.x);  // i | g
                const float E1 = __builtin_amdgcn_exp2f(a.y);  // f | o

                // delayed fc-reduce (prev step), first half: fills the
                // gate exp2->rcp window
                float p = pPend;
                p += __int_as_float(__builtin_amdgcn_update_dpp(0, __float_as_int(p), ROR(8), 0xF, 0xF, true));
                p += __int_as_float(__builtin_amdgcn_update_dpp(0, __float_as_int(p), ROR(4), 0xF, 0xF, true));

                const float r0 = __builtin_amdgcn_rcpf(1.0f + E0); // si | rg
                const float r1 = __builtin_amdgcn_rcpf(1.0f + E1); // sf | so
                const float t0 = fmaf(M2SPOS, r0, SPOS);           // -- | tgS

                // marriage across lane^16 (R13-proven ds_swizzle):
                const float x0 = swz16(t0);   // half0 receives tgS
                const float x1 = swz16(r1);   // half0 receives so

                // c/h update (valid in half0; mirror garbage-but-finite)
                c2 = fmaf(r1, c2, r0 * x0);
                const float Ec = __builtin_amdgcn_exp2f(c2);

                // delayed fc-reduce, second half + store: fills the
                // tanh(c) exp2->rcp window
                p += __int_as_float(__builtin_amdgcn_update_dpp(0, __float_as_int(p), ROR(2), 0xF, 0xF, true));
                p += __int_as_float(__builtin_amdgcn_update_dpp(0, __float_as_int(p), ROR(1), 0xF, 0xF, true));
                if (j == 0 && half == 0) *(float*)((char*)outp + offPrev) = p + fcb;

                const float rc = __builtin_amdgcn_rcpf(1.0f + Ec);
                const float m2 = -2.0f * x1;
                hn = fmaf(m2, rc, x1);

                // refresh half1's h with half0's real value (swizzle is
                // symmetric: half1 lane j receives half0 lane j's hn)
                const float ph = swz16(hn);
                hn = (half == 0) ? hn : ph;
                hbits = __float_as_int(hn);

                // stage this step's output partial + offset
                pPend   = hn * fcwj;
                offPrev = (unsigned)(tc + t4 + u) << 14;   // t * NB * 4B
            }
        }
    }

    // epilogue: flush the final pending output (t = 511)
    {
        float p = pPend;
        p += __int_as_float(__builtin_amdgcn_update_dpp(0, __float_as_int(p), ROR(8), 0xF, 0xF, true));
        p += __int_as_float(__builtin_amdgcn_update_dpp(0, __float_as_int(p), ROR(4), 0xF, 0xF, true));
        p += __int_as_float(__builtin_amdgcn_update_dpp(0, __float_as_int(p), ROR(2), 0xF, 0xF, true));
        p += __int_as_float(__builtin_amdgcn_update_dpp(0, __float_as_int(p), ROR(1), 0xF, 0xF, true));
        if (j == 0 && half == 0) *(float*)((char*)outp + offPrev) = p + fcb;
    }
}

extern "C" void kernel_launch(void* const* d_in, const int* in_sizes, int n_in,
                              void* d_out, int out_size, void* d_ws, size_t ws_size,
                              hipStream_t stream) {
    const float* X    = (const float*)d_in[0];
    const float* W_ih = (const float*)d_in[1];
    const float* W_hh = (const float*)d_in[2];
    const float* b_ih = (const float*)d_in[3];
    const float* b_hh = (const float*)d_in[4];
    const float* fc_w = (const float*)d_in[5];
    const float* fc_b = (const float*)d_in[6];
    float* out = (float*)d_out;

    const int grid = NB / RPW;   // 2048 single-wave blocks: 2 waves/SIMD
    lstm_fused<<<grid, 64, 0, stream>>>(X, W_ih, W_hh, b_ih, b_hh, fc_w, fc_b, out);
}

// Round 6
// 198.909 us; speedup vs baseline: 1.0868x; 1.0868x over previous
//
#include <hip/hip_runtime.h>

// LSTM: T=512, B=4096, IN=1, H=12.
// R16: merge the proven halves of R11 and R12, minus their measured flaws.
// Calibration from R11/R12/R15 counters: trans ops (exp2/rcp) cost ~16 cyc
// ISSUE each (quarter-rate pipe, wave64) -> R12's 10 trans = 160 of its
// 293 issue cyc. And every LDS-pipe op on the recurrence chain costs
// ~100-200 cyc wall (R12's h roundtrip; R13/R15's swizzle marriage died
// on this). So:
//  - structure: R12's proven 4 cells/wave, 1024 single-wave blocks,
//    1 wave/SIMD, launch_bounds(64,1), delayed in-lane fc + out[0]-alias
//    boundary + epilogue, X chunk staging (XPAD=68) + xq group prefetch,
//    pre-scaled gates/cell-state.
//  - h-exchange: R10/R11's DPP ror-gather (NO LDS on chain), but
//    SOURCE-PAIRED: ror results for sources (2p, 2p+1) are written into
//    the two halves of one v2f -> no splat movs; per gate 8 pk_fma over
//    8 pairs with per-lane-permuted pair weights (probe + clone
//    zero-gating exactly as R10). 15 DPP + 32 pkfma.
//  - rcp-pairing: si,sf from ONE rcp((1+Ei)(1+Ef)); rg,so from ONE
//    rcp((1+Eg)(1+Eo)). 4 rcp -> 2 rcp + 6 mul (-20 cyc issue at 16
//    cyc/trans). Products bounded (|pre-scaled gate| <~ 8 => E in
//    [2^-8, 2^8], d <= ~66k) - no overflow; rcp precision loss ~1-2 ulp,
//    absmax headroom is 6x.
//  - fc: in-lane over the gathered pairs (8 pkfma + hadd, no cross-lane
//    ops) -> pure filler for the two trans windows; delayed one step.
// Budget: issue ~300 cyc/step, chain ~130-150 all-VALU; wall 330-450 vs
// R12's 574. Predict 100-112us, VALUBusy 58-66%, conflicts ~0.

#define TT    512
#define NB    4096
#define HH    12
#define RPW   4      // cells per wave
#define CHUNK 64     // X staging chunk; TT % CHUNK == 0
#define XPAD  68     // padded x row stride (floats)

typedef float v2f __attribute__((ext_vector_type(2)));

static __device__ __forceinline__ v2f pkfma(v2f a, v2f b, v2f c) {
#if __has_builtin(__builtin_elementwise_fma)
    return __builtin_elementwise_fma(a, b, c);
#else
    v2f r; r.x = fmaf(a.x, b.x, c.x); r.y = fmaf(a.y, b.y, c.y); return r;
#endif
}

#define SNEG   (-1.44269504088896340736f)   // sigmoid pre-scale: -log2(e)
#define SPOS   ( 2.88539008177792681472f)   // tanh pre-scale: +2*log2(e)
#define M2SPOS (-5.77078016355585362944f)   // -2*SPOS

#define ROR(r) (0x120 + (r))                // DPP ctrl: row_ror:r

__global__ __launch_bounds__(64, 1)
void lstm_fused(const float* __restrict__ X,
                const float* __restrict__ W_ih,
                const float* __restrict__ W_hh,
                const float* __restrict__ b_ih,
                const float* __restrict__ b_hh,
                const float* __restrict__ fc_w,
                const float* __restrict__ fc_b,
                float* __restrict__ out)
{
    __shared__ __align__(16) float xchunk[RPW][XPAD]; // [cell-row][time]

    const int lane = threadIdx.x;        // 0..63
    const int row  = lane >> 4;          // 0..3  : cell slot
    const int j    = lane & 15;          // 0..11 real, 12..15 clone lanes
    const int cellbase = blockIdx.x * RPW;
    const int cell = cellbase + row;     // grid sized so cell < NB always

    // ---- probe DPP ror direction: sid[r] = within-row source lane of ror r
    int sid[16];
    sid[0] = j;
#define PROBE(r) sid[r] = __builtin_amdgcn_update_dpp(0, j, ROR(r), 0xF, 0xF, true);
    PROBE(1)  PROBE(2)  PROBE(3)  PROBE(4)  PROBE(5)
    PROBE(6)  PROBE(7)  PROBE(8)  PROBE(9)  PROBE(10)
    PROBE(11) PROBE(12) PROBE(13) PROBE(14) PROBE(15)
#undef PROBE

    const int jc = (j < HH) ? j : (HH - 1);   // clamp clone lanes (finite)

    // ---- source-PAIR weight tables: pair p covers sources sid[2p],sid[2p+1].
    // Zero-gate contributions from clone SOURCES for real lanes (R10 rule);
    // clone lanes keep finite clamped weights (their h is garbage-finite and
    // never read: readers zero-gate it).
    v2f wIp[8], wFp[8], wGp[8], wOp[8], fcP[8];
    const float* Wi = W_hh + (0 * HH + jc) * HH;
    const float* Wf = W_hh + (1 * HH + jc) * HH;
    const float* Wg = W_hh + (2 * HH + jc) * HH;
    const float* Wo = W_hh + (3 * HH + jc) * HH;
    #pragma unroll
    for (int p = 0; p < 8; ++p) {
        const int s0 = sid[2 * p], s1 = sid[2 * p + 1];
        const int sc0 = (s0 < HH) ? s0 : (HH - 1);
        const int sc1 = (s1 < HH) ? s1 : (HH - 1);
        const float g0 = ((j >= HH) || (s0 < HH)) ? 1.0f : 0.0f;
        const float g1 = ((j >= HH) || (s1 < HH)) ? 1.0f : 0.0f;
        wIp[p].x = g0 * SNEG * Wi[sc0];  wIp[p].y = g1 * SNEG * Wi[sc1];
        wFp[p].x = g0 * SNEG * Wf[sc0];  wFp[p].y = g1 * SNEG * Wf[sc1];
        wGp[p].x = g0 * SPOS * Wg[sc0];  wGp[p].y = g1 * SPOS * Wg[sc1];
        wOp[p].x = g0 * SNEG * Wo[sc0];  wOp[p].y = g1 * SNEG * Wo[sc1];
        fcP[p].x = (s0 < HH) ? fc_w[s0] : 0.0f;
        fcP[p].y = (s1 < HH) ? fc_w[s1] : 0.0f;
    }
    // head constants (scalar): gate init = fma(x, wx, b)
    const float wxI = SNEG * W_ih[0 * HH + jc];   // IN == 1, W_ih flat [48]
    const float wxF = SNEG * W_ih[1 * HH + jc];
    const float wxG = SPOS * W_ih[2 * HH + jc];
    const float wxO = SNEG * W_ih[3 * HH + jc];
    const float bI = SNEG * (b_ih[0 * HH + jc] + b_hh[0 * HH + jc]);
    const float bF = SNEG * (b_ih[1 * HH + jc] + b_hh[1 * HH + jc]);
    const float bG = SPOS * (b_ih[2 * HH + jc] + b_hh[2 * HH + jc]);
    const float bO = SNEG * (b_ih[3 * HH + jc] + b_hh[3 * HH + jc]);
    v2f bFCv; bFCv.x = fc_b[0]; bFCv.y = 0.0f;

    float c2 = 0.0f;     // pre-scaled cell state: SPOS * c[cell][j]
    float hn = 0.0f;     // my h element h[cell][j]  (h0 = 0)
    int hbits = 0;

    // delayed-output state (R11/R12 trick): iteration t computes
    // fc(h_t) -> out[t-1]; fake t=0 store aliases out[0], overwritten.
    unsigned offPrev = 0;
    float* const outp = out + cell;

    // prefetch chunk 0 of X into registers
    float4 gq = *(const float4*)(X + (size_t)lane * NB + cellbase);

    for (int tc = 0; tc < TT; tc += CHUNK) {
        // stage prefetched chunk to LDS (transposed/padded), prefetch next
        xchunk[0][lane] = gq.x;
        xchunk[1][lane] = gq.y;
        xchunk[2][lane] = gq.z;
        xchunk[3][lane] = gq.w;
        if (tc + CHUNK < TT)
            gq = *(const float4*)(X + (size_t)(tc + CHUNK + lane) * NB + cellbase);

        float4 xq_next = *(const float4*)&xchunk[row][0];

        for (int t4 = 0; t4 < CHUNK; t4 += 4) {
            const float4 xq = xq_next;                       // group t4
            const int nx = (t4 + 4 < CHUNK) ? (t4 + 4) : t4; // clamp tail
            xq_next = *(const float4*)&xchunk[row][nx];
            const float xs[4] = {xq.x, xq.y, xq.z, xq.w};

            #pragma unroll
            for (int u = 0; u < 4; ++u) {
                // ---- DPP gather h_{t-1}: pair p = (ror 2p, ror 2p+1),
                // DPP results land directly in v2f halves (no splat).
                v2f hp[8];
                hp[0].x = hn;   // local source (r = 0)
#define GR(r, dst) dst = __int_as_float(__builtin_amdgcn_update_dpp(0, hbits, ROR(r), 0xF, 0xF, true));
                GR(1,  hp[0].y)
                GR(2,  hp[1].x)  GR(3,  hp[1].y)
                GR(4,  hp[2].x)  GR(5,  hp[2].y)
                GR(6,  hp[3].x)  GR(7,  hp[3].y)
                GR(8,  hp[4].x)  GR(9,  hp[4].y)
                GR(10, hp[5].x)  GR(11, hp[5].y)
                GR(12, hp[6].x)  GR(13, hp[6].y)
                GR(14, hp[7].x)  GR(15, hp[7].y)
#undef GR

                // ---- 4 gate chains, 2 accumulators each (pairs 0-3 / 4-7)
                v2f aI; aI.x = fmaf(xs[u], wxI, bI); aI.y = 0.0f;
                v2f aF; aF.x = fmaf(xs[u], wxF, bF); aF.y = 0.0f;
                v2f aG; aG.x = fmaf(xs[u], wxG, bG); aG.y = 0.0f;
                v2f aO; aO.x = fmaf(xs[u], wxO, bO); aO.y = 0.0f;
                v2f bIa; bIa.x = 0.0f; bIa.y = 0.0f;
                v2f bFa = bIa, bGa = bIa, bOa = bIa;
                #pragma unroll
                for (int p = 0; p < 4; ++p) {
                    aI  = pkfma(wIp[p],     hp[p],     aI);
                    aF  = pkfma(wFp[p],     hp[p],     aF);
                    aG  = pkfma(wGp[p],     hp[p],     aG);
                    aO  = pkfma(wOp[p],     hp[p],     aO);
                    bIa = pkfma(wIp[p + 4], hp[p + 4], bIa);
                    bFa = pkfma(wFp[p + 4], hp[p + 4], bFa);
                    bGa = pkfma(wGp[p + 4], hp[p + 4], bGa);
                    bOa = pkfma(wOp[p + 4], hp[p + 4], bOa);
                }
                const v2f sI = aI + bIa;
                const v2f sF = aF + bFa;
                const v2f sG = aG + bGa;
                const v2f sO = aO + bOa;
                const float gi = sI.x + sI.y;
                const float gf = sF.x + sF.y;
                const float gg = sG.x + sG.y;
                const float go = sO.x + sO.y;

                const float Ei = __builtin_amdgcn_exp2f(gi);
                const float Ef = __builtin_amdgcn_exp2f(gf);
                const float Eg = __builtin_amdgcn_exp2f(gg);
                const float Eo = __builtin_amdgcn_exp2f(go);

                // delayed in-lane fc of h_{t-1} (pure filler, no x-lane ops)
                v2f pf = pkfma(fcP[0], hp[0], bFCv);
                pf = pkfma(fcP[1], hp[1], pf);
                pf = pkfma(fcP[2], hp[2], pf);
                pf = pkfma(fcP[3], hp[3], pf);
                pf = pkfma(fcP[4], hp[4], pf);
                pf = pkfma(fcP[5], hp[5], pf);
                pf = pkfma(fcP[6], hp[6], pf);
                pf = pkfma(fcP[7], hp[7], pf);
                const float p = pf.x + pf.y;
                if (j == 0) *(float*)((char*)outp + offPrev) = p;

                // rcp-paired activations: one rcp per gate pair
                const float pi = 1.0f + Ei;
                const float pF = 1.0f + Ef;
                const float pg = 1.0f + Eg;
                const float po = 1.0f + Eo;
                const float rif = __builtin_amdgcn_rcpf(pi * pF);
                const float rgo = __builtin_amdgcn_rcpf(pg * po);
                const float si = pF * rif;     // 1/(1+Ei)
                const float sf = pi * rif;     // 1/(1+Ef)
                const float rg = po * rgo;     // 1/(1+Eg)
                const float so = pg * rgo;     // 1/(1+Eo)

                // pre-scaled cell update
                const float tgS = fmaf(M2SPOS, rg, SPOS);
                c2 = fmaf(sf, c2, si * tgS);
                const float Ec = __builtin_amdgcn_exp2f(c2);   // exp2(SPOS*c)
                const float rc = __builtin_amdgcn_rcpf(1.0f + Ec);
                const float m2so = -2.0f * so;
                hn = fmaf(m2so, rc, so);
                hbits = __float_as_int(hn);

                offPrev = (unsigned)(tc + t4 + u) << 14;   // t * NB * 4B
            }
        }
    }

    // epilogue: fc(h_511) -> out[511] (gather final h pairs once more)
    {
        v2f hp[8];
        hp[0].x = hn;
#define GR(r, dst) dst = __int_as_float(__builtin_amdgcn_update_dpp(0, hbits, ROR(r), 0xF, 0xF, true));
        GR(1,  hp[0].y)
        GR(2,  hp[1].x)  GR(3,  hp[1].y)
        GR(4,  hp[2].x)  GR(5,  hp[2].y)
        GR(6,  hp[3].x)  GR(7,  hp[3].y)
        GR(8,  hp[4].x)  GR(9,  hp[4].y)
        GR(10, hp[5].x)  GR(11, hp[5].y)
        GR(12, hp[6].x)  GR(13, hp[6].y)
        GR(14, hp[7].x)  GR(15, hp[7].y)
#undef GR
        v2f pf = pkfma(fcP[0], hp[0], bFCv);
        pf = pkfma(fcP[1], hp[1], pf);
        pf = pkfma(fcP[2], hp[2], pf);
        pf = pkfma(fcP[3], hp[3], pf);
        pf = pkfma(fcP[4], hp[4], pf);
        pf = pkfma(fcP[5], hp[5], pf);
        pf = pkfma(fcP[6], hp[6], pf);
        pf = pkfma(fcP[7], hp[7], pf);
        const float p = pf.x + pf.y;
        if (j == 0) *(float*)((char*)outp + offPrev) = p;
    }
}

extern "C" void kernel_launch(void* const* d_in, const int* in_sizes, int n_in,
                              void* d_out, int out_size, void* d_ws, size_t ws_size,
                              hipStream_t stream) {
    const float* X    = (const float*)d_in[0];
    const float* W_ih = (const float*)d_in[1];
    const float* W_hh = (const float*)d_in[2];
    const float* b_ih = (const float*)d_in[3];
    const float* b_hh = (const float*)d_in[4];
    const float* fc_w = (const float*)d_in[5];
    const float* fc_b = (const float*)d_in[6];
    float* out = (float*)d_out;

    const int grid = NB / RPW;   // 1024 single-wave blocks: every SIMD busy
    lstm_fused<<<grid, 64, 0, stream>>>(X, W_ih, W_hh, b_ih, b_hh, fc_w, fc_b, out);
}

// Round 7
// 176.777 us; speedup vs baseline: 1.2229x; 1.1252x over previous
//
#include <hip/hip_runtime.h>

// LSTM: T=512, B=4096, IN=1, H=12.
// R17 = R12 (best proven: 122.5us) + register-residency fix + rcp-pairing.
//
// Residency theory (from R16 post-mortem): every kernel this session
// reported VGPR_Count (52-72) far below the live-value count of its
// weight tables (R12: tables ~60 regs + state ~25 at VGPR=56; R16: ~96
// at VGPR=72) -> the backend's occupancy heuristic was NOT keeping the
// loop-invariant weights resident; measured issue exceeded hand-counts
// by ~70-125 cyc/step in every round = per-step L1 reloads + vmcnt
// stalls. __launch_bounds__(64,1) only sets MIN waves/EU (removes the
// resource cap) but doesn't change the allocator's occupancy target.
// Fix: amdgpu_waves_per_eu(1,1) - the kernel genuinely runs 1 wave/SIMD
// (1024 single-wave blocks on 1024 SIMDs), so license all 512 VGPRs.
// TELL: VGPR_Count should jump to ~110-180. If it stays ~56 the theory
// is dead and the LDS h round-trip chain is the true floor.
//
// rcp-pairing (numerics validated in R16, absmax 1.95e-3 << 6e-3):
// si,sf from ONE rcp((1+Ei)(1+Ef)); rg,so from ONE rcp((1+Eg)(1+Eo)).
// 5 rcp -> 3 rcp + 6 mul = -20 cyc issue, +~8 cyc chain (filler-covered).
// Bounds: |pre-scaled gate| <~ 15 -> E <= 2^15, product <= 2^30: finite.
//
// R12 structure (unchanged, proven):
//  - 4 cells/wave (16-lane rows; lanes 12-15 clones), 1024 blocks.
//  - h exchange via LDS: hn -> ds_write_b32 (slot j, rows on stride-20),
//    read back 3x broadcast ds_read_b128 (conflict-free).
//  - in-lane pairwise matvec: per gate init (x-proj+bias packed) + 6
//    pkfma over (h[2k],h[2k+1]) pairs straight from b128 subregs.
//  - fc dot in-lane, DELAYED one step (fills the exp2->rcp windows);
//    fake t=0 store aliases out[0], overwritten next step; epilogue
//    flushes t=511.
//  - pre-scaled gates (sigmoid -log2e, tanh-g +2log2e) -> activations
//    are rcp(1+exp2(g)); cell state carried as c2 = 2log2e*c.
//  - X staged per chunk to LDS transposed+padded (XPAD=68), global
//    prefetch one chunk ahead, xq b128 one 4-step group ahead.
// Predicted: dur 122.5 -> ~100-110us, VALUBusy ~45-52%, VGPR 110-180.

#define TT    512
#define NB    4096
#define HH    12
#define RPW   4      // cells per wave
#define CHUNK 64     // X staging chunk; TT % CHUNK == 0
#define XPAD  68     // padded x row stride (floats)
#define HSTR  20     // h row stride (floats): rows land on disjoint banks

typedef float v2f __attribute__((ext_vector_type(2)));
typedef float v4f __attribute__((ext_vector_type(4)));

static __device__ __forceinline__ v2f pkfma(v2f a, v2f b, v2f c) {
#if __has_builtin(__builtin_elementwise_fma)
    return __builtin_elementwise_fma(a, b, c);
#else
    v2f r; r.x = fmaf(a.x, b.x, c.x); r.y = fmaf(a.y, b.y, c.y); return r;
#endif
}

#define SNEG   (-1.44269504088896340736f)   // sigmoid pre-scale: -log2(e)
#define SPOS   ( 2.88539008177792681472f)   // tanh pre-scale: +2*log2(e)
#define M2SPOS (-5.77078016355585362944f)   // -2*SPOS

__global__ __launch_bounds__(64)
__attribute__((amdgpu_waves_per_eu(1, 1)))
void lstm_fused(const float* __restrict__ X,
                const float* __restrict__ W_ih,
                const float* __restrict__ W_hh,
                const float* __restrict__ b_ih,
                const float* __restrict__ b_hh,
                const float* __restrict__ fc_w,
                const float* __restrict__ fc_b,
                float* __restrict__ out)
{
    __shared__ __align__(16) float xchunk[RPW][XPAD]; // [row][time], padded
    __shared__ __align__(16) float hsh[RPW][HSTR];    // [row][h-slot]

    const int lane = threadIdx.x;        // 0..63
    const int row  = lane >> 4;          // 0..3  : cell slot
    const int j    = lane & 15;          // 0..11 real, 12..15 clone lanes
    const int cellbase = blockIdx.x * RPW;
    const int cell = cellbase + row;     // grid sized so cell < NB always

    const int jc = (j < HH) ? j : (HH - 1);   // clamp clone lanes (finite)

    // ---- in-lane pairwise weights: per gate, 6 v2f of (W[s],W[s+1]),
    // pre-scaled (i,f,o: SNEG; g: SPOS). Rows of W_hh are contiguous [12].
    v2f wI[6], wF[6], wG[6], wO[6], fcv[6];
    #pragma unroll
    for (int k = 0; k < 6; ++k) {
        const float* r0 = W_hh + (0 * HH + jc) * HH + 2 * k;
        const float* r1 = W_hh + (1 * HH + jc) * HH + 2 * k;
        const float* r2 = W_hh + (2 * HH + jc) * HH + 2 * k;
        const float* r3 = W_hh + (3 * HH + jc) * HH + 2 * k;
        wI[k].x = SNEG * r0[0];  wI[k].y = SNEG * r0[1];
        wF[k].x = SNEG * r1[0];  wF[k].y = SNEG * r1[1];
        wG[k].x = SPOS * r2[0];  wG[k].y = SPOS * r2[1];
        wO[k].x = SNEG * r3[0];  wO[k].y = SNEG * r3[1];
        fcv[k].x = fc_w[2 * k];  fcv[k].y = fc_w[2 * k + 1];
    }
    // head constants: init acc_g = pkfma((x,x), (wx_g,0), (b_g,0))
    v2f wxI, wxF, wxG, wxO, bI, bF, bG, bO, bFC;
    wxI.x = SNEG * W_ih[0 * HH + jc];  wxI.y = 0.0f;
    wxF.x = SNEG * W_ih[1 * HH + jc];  wxF.y = 0.0f;
    wxG.x = SPOS * W_ih[2 * HH + jc];  wxG.y = 0.0f;
    wxO.x = SNEG * W_ih[3 * HH + jc];  wxO.y = 0.0f;
    bI.x = SNEG * (b_ih[0 * HH + jc] + b_hh[0 * HH + jc]);  bI.y = 0.0f;
    bF.x = SNEG * (b_ih[1 * HH + jc] + b_hh[1 * HH + jc]);  bF.y = 0.0f;
    bG.x = SPOS * (b_ih[2 * HH + jc] + b_hh[2 * HH + jc]);  bG.y = 0.0f;
    bO.x = SNEG * (b_ih[3 * HH + jc] + b_hh[3 * HH + jc]);  bO.y = 0.0f;
    bFC.x = fc_b[0];  bFC.y = 0.0f;     // fc bias folded into fc init

    float c2 = 0.0f;     // pre-scaled cell state: SPOS * c[cell][j]
    float hn = 0.0f;     // my h element h[cell][j]  (h0 = 0)

    float* const hrow = &hsh[row][0];
    const int wslot = j;   // clones dump to 12..15 (never read)

    // delayed-output state (R11 trick): iteration t computes fc(h_{t-1});
    // first (fake) store aliases out[0][cell], overwritten next iteration.
    unsigned offPrev = 0;
    float* const outp = out + cell;

    // initial h0 = 0 into LDS (same-wave DS in-order vs later reads)
    hrow[wslot] = 0.0f;
    __builtin_amdgcn_wave_barrier();

    // prefetch chunk 0 of X into registers
    float4 gq = *(const float4*)(X + (size_t)lane * NB + cellbase);

    for (int tc = 0; tc < TT; tc += CHUNK) {
        // stage prefetched chunk to LDS (transposed/padded), prefetch next
        xchunk[0][lane] = gq.x;
        xchunk[1][lane] = gq.y;
        xchunk[2][lane] = gq.z;
        xchunk[3][lane] = gq.w;
        if (tc + CHUNK < TT)
            gq = *(const float4*)(X + (size_t)(tc + CHUNK + lane) * NB + cellbase);

        float4 xq_next = *(const float4*)&xchunk[row][0];

        for (int t4 = 0; t4 < CHUNK; t4 += 4) {
            const float4 xq = xq_next;                       // group t4
            const int nx = (t4 + 4 < CHUNK) ? (t4 + 4) : t4; // clamp tail
            xq_next = *(const float4*)&xchunk[row][nx];      // prefetch next
            const float xs[4] = {xq.x, xq.y, xq.z, xq.w};

            #pragma unroll
            for (int u = 0; u < 4; ++u) {
                // broadcast-read the row's h_{t-1} (3x ds_read_b128,
                // disjoint banks across rows by stride-20 layout)
                const v4f ha = *(const v4f*)&hrow[0];
                const v4f hb = *(const v4f*)&hrow[4];
                const v4f hc = *(const v4f*)&hrow[8];
                v2f hp0; hp0.x = ha.x; hp0.y = ha.y;
                v2f hp1; hp1.x = ha.z; hp1.y = ha.w;
                v2f hp2; hp2.x = hb.x; hp2.y = hb.y;
                v2f hp3; hp3.x = hb.z; hp3.y = hb.w;
                v2f hp4; hp4.x = hc.x; hp4.y = hc.y;
                v2f hp5; hp5.x = hc.z; hp5.y = hc.w;

                // gate chains: packed init (x-proj + bias), then 6 pair fmas
                v2f xvv; xvv.x = xs[u]; xvv.y = xs[u];
                v2f aI = pkfma(xvv, wxI, bI);
                v2f aF = pkfma(xvv, wxF, bF);
                v2f aG = pkfma(xvv, wxG, bG);
                v2f aO = pkfma(xvv, wxO, bO);
                // fc of h_{t-1} (delayed output), bias pre-folded: pure
                // filler for the trans windows below
                v2f pf = pkfma(fcv[0], hp0, bFC);
                aI = pkfma(wI[0], hp0, aI);  aF = pkfma(wF[0], hp0, aF);
                aG = pkfma(wG[0], hp0, aG);  aO = pkfma(wO[0], hp0, aO);
                aI = pkfma(wI[1], hp1, aI);  aF = pkfma(wF[1], hp1, aF);
                aG = pkfma(wG[1], hp1, aG);  aO = pkfma(wO[1], hp1, aO);
                pf = pkfma(fcv[1], hp1, pf);
                aI = pkfma(wI[2], hp2, aI);  aF = pkfma(wF[2], hp2, aF);
                aG = pkfma(wG[2], hp2, aG);  aO = pkfma(wO[2], hp2, aO);
                pf = pkfma(fcv[2], hp2, pf);
                aI = pkfma(wI[3], hp3, aI);  aF = pkfma(wF[3], hp3, aF);
                aG = pkfma(wG[3], hp3, aG);  aO = pkfma(wO[3], hp3, aO);
                pf = pkfma(fcv[3], hp3, pf);
                aI = pkfma(wI[4], hp4, aI);  aF = pkfma(wF[4], hp4, aF);
                aG = pkfma(wG[4], hp4, aG);  aO = pkfma(wO[4], hp4, aO);
                pf = pkfma(fcv[4], hp4, pf);
                aI = pkfma(wI[5], hp5, aI);  aF = pkfma(wF[5], hp5, aF);
                aG = pkfma(wG[5], hp5, aG);  aO = pkfma(wO[5], hp5, aO);
                pf = pkfma(fcv[5], hp5, pf);

                const float gi = aI.x + aI.y;
                const float gf = aF.x + aF.y;
                const float gg = aG.x + aG.y;
                const float go = aO.x + aO.y;

                const float Ei = __builtin_amdgcn_exp2f(gi);
                const float Ef = __builtin_amdgcn_exp2f(gf);
                const float Eg = __builtin_amdgcn_exp2f(gg);
                const float Eo = __builtin_amdgcn_exp2f(go);

                // delayed output store: fills the gate exp2->rcp window
                const float p = pf.x + pf.y;
                if (j == 0) *(float*)((char*)outp + offPrev) = p;

                // rcp-paired activations: one rcp per gate pair
                const float dI = 1.0f + Ei;
                const float dF = 1.0f + Ef;
                const float dG = 1.0f + Eg;
                const float dO = 1.0f + Eo;
                const float rif = __builtin_amdgcn_rcpf(dI * dF);
                const float rgo = __builtin_amdgcn_rcpf(dG * dO);
                const float si = dF * rif;     // 1/(1+Ei)
                const float sf = dI * rif;     // 1/(1+Ef)
                const float rg = dO * rgo;     // 1/(1+Eg)
                const float so = dG * rgo;     // 1/(1+Eo)

                // pre-scaled cell update
                const float tgS = fmaf(M2SPOS, rg, SPOS);
                c2 = fmaf(sf, c2, si * tgS);
                const float Ec = __builtin_amdgcn_exp2f(c2);   // exp2(SPOS*c)
                const float rc = __builtin_amdgcn_rcpf(1.0f + Ec);
                const float m2so = -2.0f * so;
                hn = fmaf(m2so, rc, so);

                // publish h_t for next iteration's broadcast read
                hrow[wslot] = hn;
                __builtin_amdgcn_wave_barrier();

                offPrev = (unsigned)(tc + t4 + u) << 14;   // t * NB * 4B
            }
        }
    }

    // epilogue: fc(h_511) -> out[511]
    {
        const v4f ha = *(const v4f*)&hrow[0];
        const v4f hb = *(const v4f*)&hrow[4];
        const v4f hc = *(const v4f*)&hrow[8];
        v2f hp0; hp0.x = ha.x; hp0.y = ha.y;
        v2f hp1; hp1.x = ha.z; hp1.y = ha.w;
        v2f hp2; hp2.x = hb.x; hp2.y = hb.y;
        v2f hp3; hp3.x = hb.z; hp3.y = hb.w;
        v2f hp4; hp4.x = hc.x; hp4.y = hc.y;
        v2f hp5; hp5.x = hc.z; hp5.y = hc.w;
        v2f pf = pkfma(fcv[0], hp0, bFC);
        pf = pkfma(fcv[1], hp1, pf);
        pf = pkfma(fcv[2], hp2, pf);
        pf = pkfma(fcv[3], hp3, pf);
        pf = pkfma(fcv[4], hp4, pf);
        pf = pkfma(fcv[5], hp5, pf);
        const float p = pf.x + pf.y;
        if (j == 0) *(float*)((char*)outp + offPrev) = p;
    }
}

extern "C" void kernel_launch(void* const* d_in, const int* in_sizes, int n_in,
                              void* d_out, int out_size, void* d_ws, size_t ws_size,
                              hipStream_t stream) {
    const float* X    = (const float*)d_in[0];
    const float* W_ih = (const float*)d_in[1];
    const float* W_hh = (const float*)d_in[2];
    const float* b_ih = (const float*)d_in[3];
    const float* b_hh = (const float*)d_in[4];
    const float* fc_w = (const float*)d_in[5];
    const float* fc_b = (const float*)d_in[6];
    float* out = (float*)d_out;

    const int grid = NB / RPW;   // 1024 single-wave blocks: every SIMD busy
    lstm_fused<<<grid, 64, 0, stream>>>(X, W_ih, W_hh, b_ih, b_hh, fc_w, fc_b, out);
}